// Round 2
// baseline (273.580 us; speedup 1.0000x reference)
//
#include <hip/hip_runtime.h>

// apply_cdna_kernels: out[n,b,c,h,w] = sum_{kh,kw} images[b,h+kh-2,w+kw-2,c] * kernels[b,kh,kw,n]
// images: [64,128,128,3] f32   kernels: [64,5,5,10] f32   out: [10,64,3,128,128] f32
//
// R3: all-N-per-block (kills R1's 80MB image refetch across XCD L2s) +
//     R1's vectorized access (ds_read_b128 / global_store_dwordx4).
//  - block = 8h x 128w tile, staged ONCE into LDS
//  - thread = 1h x 4w x 3c, pixel window (5 rows x 24 floats = 120 f) held in
//    VGPRs across the n-loop -> LDS read once (30x b128), zero per-n LDS traffic
//  - n-loop (#pragma unroll 1): 25 uniform weights via s_load (s-cache hit for
//    n>0), 300 FMA, 3x dwordx4 store per iteration
//  - weights stay in SGPRs; no lgkmcnt stall inside the FMA block

#define B_  64
#define H_  128
#define W_  128
#define C_  3
#define N_  10
#define KH_ 5
#define KW_ 5
#define TH_ 8                  // tile height (full W width)
#define LDS_ROWS (TH_ + 4)     // 12 rows incl. halo
#define ROW_F ((W_ + 4) * C_)  // 132 px * 3 = 396 floats per LDS row
#define ROW_VALID (W_ * C_)    // 384 valid floats per global image row
#define HW_ (H_ * W_)          // 16384

__global__ __launch_bounds__(256, 3) void cdna_apply_kernel(
    const float* __restrict__ images,
    const float* __restrict__ kernels,
    float* __restrict__ out)
{
    __shared__ __align__(16) float s_img[LDS_ROWS * ROW_F];

    const int tid = threadIdx.x;
    const int ht  = blockIdx.x;   // 16
    const int b   = blockIdx.y;   // 64
    const int y0  = ht * TH_;

    // ---- stage image tile (12 rows x 99 float4; zero-padded halo) ----
    const float* __restrict__ ib = images + (long)b * (H_ * W_ * C_);
    for (int i = tid; i < LDS_ROWS * (ROW_F / 4); i += 256) {
        const int r  = i / (ROW_F / 4);        // LDS row 0..11
        const int q  = i - r * (ROW_F / 4);    // float4 index in row, 0..98
        const int y  = y0 + r - 2;
        float v0 = 0.f, v1 = 0.f, v2 = 0.f, v3 = 0.f;
        if ((unsigned)y < (unsigned)H_) {
            const float* grow = ib + (long)y * ROW_VALID;
            const int f0 = q * 4 - 6;          // offset into 384-float global row (even)
            if (f0 >= 0 && f0 <= ROW_VALID - 4) {
                const float2 a  = *(const float2*)(grow + f0);
                const float2 c2 = *(const float2*)(grow + f0 + 2);
                v0 = a.x; v1 = a.y; v2 = c2.x; v3 = c2.y;
            } else {
                if (f0 + 0 >= 0 && f0 + 0 < ROW_VALID) v0 = grow[f0 + 0];
                if (f0 + 1 >= 0 && f0 + 1 < ROW_VALID) v1 = grow[f0 + 1];
                if (f0 + 2 >= 0 && f0 + 2 < ROW_VALID) v2 = grow[f0 + 2];
                if (f0 + 3 >= 0 && f0 + 3 < ROW_VALID) v3 = grow[f0 + 3];
            }
        }
        *(float4*)(&s_img[r * ROW_F + q * 4]) = make_float4(v0, v1, v2, v3);
    }
    __syncthreads();

    const int tx = tid & 31;      // 4w column group
    const int ty = tid >> 5;      // 0..7 output row within tile

    // ---- pull this thread's whole pixel window into registers ----
    // output row y0+ty needs image rows (y0+ty-2 .. y0+ty+2) = LDS rows ty..ty+4
    // cols x = 4*tx-2 .. 4*tx+5 -> LDS float offset tx*12, 24 floats (6x b128)
    float px[KH_][24];
    #pragma unroll
    for (int r = 0; r < KH_; ++r) {
        const float4* rp = (const float4*)&s_img[(ty + r) * ROW_F + tx * 12];
        #pragma unroll
        for (int j = 0; j < 6; ++j) {
            const float4 t = rp[j];
            px[r][j * 4 + 0] = t.x; px[r][j * 4 + 1] = t.y;
            px[r][j * 4 + 2] = t.z; px[r][j * 4 + 3] = t.w;
        }
    }

    const float* __restrict__ kb = kernels + (long)b * (KH_ * KW_ * N_);
    const int h = y0 + ty;
    float* ob0 = out + (long)b * (C_ * HW_) + (long)h * W_ + tx * 4;
    const long nstride = (long)B_ * C_ * HW_;

    #pragma unroll 1
    for (int n = 0; n < N_; ++n) {
        // 25 block-uniform weights -> SGPRs (s-cache hit after first iter)
        float wt[KH_ * KW_];
        #pragma unroll
        for (int k = 0; k < KH_ * KW_; ++k)
            wt[k] = kb[k * N_ + n];

        float acc[12];                         // [c*4 + w]
        #pragma unroll
        for (int i = 0; i < 12; ++i) acc[i] = 0.f;

        #pragma unroll
        for (int kh = 0; kh < KH_; ++kh) {
            #pragma unroll
            for (int kw = 0; kw < KW_; ++kw) {
                const float wgt = wt[kh * KW_ + kw];
                #pragma unroll
                for (int w = 0; w < 4; ++w)
                    #pragma unroll
                    for (int c = 0; c < C_; ++c)
                        acc[c * 4 + w] = fmaf(px[kh][(kw + w) * 3 + c], wgt, acc[c * 4 + w]);
            }
        }

        float* ob = ob0 + n * nstride;
        #pragma unroll
        for (int c = 0; c < C_; ++c)
            *(float4*)(ob + (long)c * HW_) =
                make_float4(acc[c*4+0], acc[c*4+1], acc[c*4+2], acc[c*4+3]);
    }
}

extern "C" void kernel_launch(void* const* d_in, const int* in_sizes, int n_in,
                              void* d_out, int out_size, void* d_ws, size_t ws_size,
                              hipStream_t stream) {
    const float* images  = (const float*)d_in[0];
    const float* kernels = (const float*)d_in[1];
    float* out = (float*)d_out;

    dim3 grid(H_ / TH_, B_);   // 16 x 64 = 1024 blocks
    cdna_apply_kernel<<<grid, 256, 0, stream>>>(images, kernels, out);
}

// Round 3
// 172.008 us; speedup vs baseline: 1.5905x; 1.5905x over previous
//
#include <hip/hip_runtime.h>

// apply_cdna_kernels: out[n,b,c,h,w] = sum_{kh,kw} images[b,h+kh-2,w+kw-2,c] * kernels[b,kh,kw,n]
// images: [64,128,128,3] f32   kernels: [64,5,5,10] f32   out: [10,64,3,128,128] f32
//
// R4: R3's spill (VGPR 84 < 120-float px window -> 250MB scratch FETCH, 283MB
// WRITE) is the bug. Keep all-N-per-block image reuse, shrink live set:
//  - block = 16h x 128w tile staged ONCE (31.7KB LDS), all 10 n per block
//  - thread = 2h x 4w x 3c; per n: 25 SGPR weights, 6-row sliding window
//    (36x ds_read_b128, conflict-free: lane stride 48B), 600 FMA, 6x dwordx4
//  - live set ~60 VGPR (24 acc + 24 px + addr); launch_bounds(256,2) gives the
//    allocator a 256-VGPR budget so it never spills for an occupancy boundary
//  - grid 512 = 2 blocks/CU = 2 waves/SIMD; floors: write 20us, VALU 10us, LDS 10us

#define B_  64
#define H_  128
#define W_  128
#define C_  3
#define N_  10
#define KH_ 5
#define KW_ 5
#define TH_ 16                 // tile height (full W width)
#define LDS_ROWS (TH_ + 4)     // 20 rows incl. halo
#define ROW_F ((W_ + 4) * C_)  // 132 px * 3 = 396 floats per row (1584B, 16B-aligned)
#define ROW_VALID (W_ * C_)    // 384 valid floats per global image row
#define HW_ (H_ * W_)          // 16384

__global__ __launch_bounds__(256, 2) void cdna_apply_kernel(
    const float* __restrict__ images,
    const float* __restrict__ kernels,
    float* __restrict__ out)
{
    __shared__ __align__(16) float s_img[LDS_ROWS * ROW_F];

    const int tid = threadIdx.x;
    const int ht  = blockIdx.x;   // 8
    const int b   = blockIdx.y;   // 64
    const int y0  = ht * TH_;

    // ---- stage image tile (20 rows x 99 float4; zero-padded halo), once ----
    const float* __restrict__ ib = images + (long)b * (H_ * W_ * C_);
    for (int i = tid; i < LDS_ROWS * (ROW_F / 4); i += 256) {
        const int r  = i / (ROW_F / 4);        // LDS row 0..19
        const int q  = i - r * (ROW_F / 4);    // float4 index in row, 0..98
        const int y  = y0 + r - 2;
        float v0 = 0.f, v1 = 0.f, v2 = 0.f, v3 = 0.f;
        if ((unsigned)y < (unsigned)H_) {
            const float* grow = ib + (long)y * ROW_VALID;
            const int f0 = q * 4 - 6;          // offset into 384-float global row (even)
            if (f0 >= 0 && f0 <= ROW_VALID - 4) {
                const float2 a  = *(const float2*)(grow + f0);
                const float2 c2 = *(const float2*)(grow + f0 + 2);
                v0 = a.x; v1 = a.y; v2 = c2.x; v3 = c2.y;
            } else {
                if (f0 + 0 >= 0 && f0 + 0 < ROW_VALID) v0 = grow[f0 + 0];
                if (f0 + 1 >= 0 && f0 + 1 < ROW_VALID) v1 = grow[f0 + 1];
                if (f0 + 2 >= 0 && f0 + 2 < ROW_VALID) v2 = grow[f0 + 2];
                if (f0 + 3 >= 0 && f0 + 3 < ROW_VALID) v3 = grow[f0 + 3];
            }
        }
        *(float4*)(&s_img[r * ROW_F + q * 4]) = make_float4(v0, v1, v2, v3);
    }
    __syncthreads();

    const int tx = tid & 31;      // 4w column group: cols 4tx..4tx+3
    const int ty = tid >> 5;      // 0..7 -> rows 2ty, 2ty+1 within tile

    const float* __restrict__ kb = kernels + (long)b * (KH_ * KW_ * N_);
    const int h0 = y0 + 2 * ty;
    float* ob0 = out + (long)b * (C_ * HW_) + (long)h0 * W_ + tx * 4;
    const long nstride = (long)B_ * C_ * HW_;

    #pragma unroll 1
    for (int n = 0; n < N_; ++n) {
        // 25 block-uniform weights -> SGPRs (scalar-cache hit after n=0)
        float wt[KH_ * KW_];
        #pragma unroll
        for (int k = 0; k < KH_ * KW_; ++k)
            wt[k] = kb[k * N_ + n];

        float acc0[12], acc1[12];              // [c*4 + w] for rows h0, h0+1
        #pragma unroll
        for (int i = 0; i < 12; ++i) { acc0[i] = 0.f; acc1[i] = 0.f; }

        // LDS rows 2ty + r, r=0..5: row r feeds h0 (kh=r, r<5) and h0+1 (kh=r-1, r>=1)
        #pragma unroll
        for (int r = 0; r < 6; ++r) {
            const float4* rp = (const float4*)&s_img[(2 * ty + r) * ROW_F + tx * 12];
            float px[24];                      // pixels x=4tx-2..4tx+5, 3 c each
            #pragma unroll
            for (int j = 0; j < 6; ++j) {      // 6x ds_read_b128, conflict-free
                const float4 t = rp[j];
                px[j * 4 + 0] = t.x; px[j * 4 + 1] = t.y;
                px[j * 4 + 2] = t.z; px[j * 4 + 3] = t.w;
            }
            if (r < 5) {
                #pragma unroll
                for (int kw = 0; kw < KW_; ++kw) {
                    const float wgt = wt[r * KW_ + kw];
                    #pragma unroll
                    for (int w = 0; w < 4; ++w)
                        #pragma unroll
                        for (int c = 0; c < C_; ++c)
                            acc0[c * 4 + w] = fmaf(px[(kw + w) * 3 + c], wgt, acc0[c * 4 + w]);
                }
            }
            if (r >= 1) {
                #pragma unroll
                for (int kw = 0; kw < KW_; ++kw) {
                    const float wgt = wt[(r - 1) * KW_ + kw];
                    #pragma unroll
                    for (int w = 0; w < 4; ++w)
                        #pragma unroll
                        for (int c = 0; c < C_; ++c)
                            acc1[c * 4 + w] = fmaf(px[(kw + w) * 3 + c], wgt, acc1[c * 4 + w]);
                }
            }
        }

        // 6x global_store_dwordx4: contiguous 512B per (n,c,h) row across the wave
        float* ob = ob0 + n * nstride;
        #pragma unroll
        for (int c = 0; c < C_; ++c) {
            *(float4*)(ob + (long)c * HW_)      = make_float4(acc0[c*4+0], acc0[c*4+1], acc0[c*4+2], acc0[c*4+3]);
            *(float4*)(ob + (long)c * HW_ + W_) = make_float4(acc1[c*4+0], acc1[c*4+1], acc1[c*4+2], acc1[c*4+3]);
        }
    }
}

extern "C" void kernel_launch(void* const* d_in, const int* in_sizes, int n_in,
                              void* d_out, int out_size, void* d_ws, size_t ws_size,
                              hipStream_t stream) {
    const float* images  = (const float*)d_in[0];
    const float* kernels = (const float*)d_in[1];
    float* out = (float*)d_out;

    dim3 grid(H_ / TH_, B_);   // 8 x 64 = 512 blocks, 2 per CU
    cdna_apply_kernel<<<grid, 256, 0, stream>>>(images, kernels, out);
}